// Round 5
// baseline (292.732 us; speedup 1.0000x reference)
//
#include <hip/hip_runtime.h>
#include <hip/hip_bf16.h>
#include <math.h>

typedef unsigned short u16;
typedef short bf16x8 __attribute__((ext_vector_type(8)));
typedef float f32x4 __attribute__((ext_vector_type(4)));

#define NB 8
#define NN 56          // h == w
#define M2 112         // 2n
#define EMB 192
#define D1 576
#define TOK (NB*NN*NN) // 25088

__device__ __forceinline__ float bf2f(unsigned int u) {
    union { unsigned int i; float f; } v; v.i = u << 16; return v.f;
}
__device__ __forceinline__ u16 f2bf(float f) {
    union { float f; unsigned int i; } v; v.f = f;
    unsigned int x = v.i;
    return (u16)((x + 0x7fffu + ((x >> 16) & 1u)) >> 16);
}
__device__ __forceinline__ float silu(float x) {
    return x / (1.0f + __expf(-x));
}
__device__ __forceinline__ void async16(void* lds, const void* g) {
    __builtin_amdgcn_global_load_lds(
        (const __attribute__((address_space(1))) void*)g,
        (__attribute__((address_space(3))) void*)lds, 16, 0, 0);
}

// ---------------- K0: fp32 -> bf16 convert (x, pw, qw, vw, ow) ------------
#define XCH (TOK*EMB/4)
#define WCH (D1*EMB/4)
__global__ __launch_bounds__(256) void convert_kernel(
    const float* __restrict__ x,
    const float* __restrict__ pw, const float* __restrict__ qw,
    const float* __restrict__ vw, const float* __restrict__ ow,
    u16* __restrict__ xb, u16* __restrict__ wb, u16* __restrict__ owb)
{
    int tid = blockIdx.x * 256 + threadIdx.x;
    const float* src; u16* dst; int off;
    if (tid < XCH) { src = x; dst = xb; off = tid; }
    else {
        int r = tid - XCH;
        int seg = r / WCH; off = r % WCH;
        if (seg == 0)      { src = pw; dst = wb; }
        else if (seg == 1) { src = qw; dst = wb + D1*EMB; }
        else if (seg == 2) { src = vw; dst = wb + 2*D1*EMB; }
        else if (seg == 3) { src = ow; dst = owb; }
        else return;
    }
    float4 f = *(const float4*)(src + off * 4);
    ushort4 o;
    o.x = f2bf(f.x); o.y = f2bf(f.y); o.z = f2bf(f.z); o.w = f2bf(f.w);
    *(ushort4*)(dst + off * 4) = o;
}

// ---------------- K1: RPE MLP + decay -> A1, A2 (fp32, 112 x 576 each) ----
__global__ __launch_bounds__(576) void rpe_kernel(
    const float* __restrict__ slope,
    const float* w0a, const float* b0a, const float* wsa, const float* bsa,
    const float* woa, const float* boa,
    const float* w0b, const float* b0b, const float* wsb, const float* bsb,
    const float* wob, const float* bob,
    float* __restrict__ A1, float* __restrict__ A2)
{
    int wq  = blockIdx.x / M2;
    int row = blockIdx.x % M2;
    const float* w0 = wq ? w0b : w0a;  const float* b0 = wq ? b0b : b0a;
    const float* ws = wq ? wsb : wsa;  const float* bs = wq ? bsb : bsa;
    const float* wo = wq ? wob : woa;  const float* bo = wq ? bob : boa;
    float* A = wq ? A2 : A1;

    float tval = (row == 0 || row == 56) ? 0.0f
               : (row < 56 ? (float)row : -(float)(row - 56));
    int kexp = (row == 0 || row == 56) ? 0 : (row < 56 ? row : 112 - row);

    __shared__ float h[32], g[32];
    int t = threadIdx.x;
    if (t < 32) h[t] = tval * w0[t] + b0[t];
    __syncthreads();
    for (int L = 0; L < 3; L++) {
        if (t < 32) g[t] = fmaxf(h[t], 0.0f);
        __syncthreads();
        float hn = 0.0f;
        if (t < 32) {
            hn = bs[L * 32 + t];
            for (int k = 0; k < 32; k++)
                hn = fmaf(g[k], ws[(L * 32 + t) * 32 + k], hn);
        }
        __syncthreads();
        if (t < 32) h[t] = hn;
        __syncthreads();
    }
    if (t < 32) g[t] = fmaxf(h[t], 0.0f);
    __syncthreads();

    float o = bo[t];
    for (int k = 0; k < 32; k++)
        o = fmaf(g[k], wo[t * 32 + k], o);

    float sl = slope[t];
    sl = 0.95f + 0.05f * fminf(fmaxf(sl, 0.0f), 1.0f);
    float dec = powf(sl, (float)kexp);
    A[row * D1 + t] = o * dec;
}

// ---------------- K2: MFMA proj --------------------------------------------
__global__ __launch_bounds__(256) void proj_kernel(
    const u16* __restrict__ xb, const u16* __restrict__ wb,
    const float* __restrict__ pb, const float* __restrict__ qb,
    const float* __restrict__ vb,
    u16* __restrict__ P, u16* __restrict__ QV)
{
    __shared__ u16 lds[20480];          // 40 KB: As 8192 u16, Bs 12288 u16
    u16* As = lds;
    u16* Bs = lds + 8192;
    int m0 = blockIdx.x * 128, n0 = blockIdx.y * 64;
    int t = threadIdx.x;
    int l = t & 63, wave = t >> 6;
    int wm = wave >> 1, wn = wave & 1;
    int col16 = l & 15, q = l >> 4;

    f32x4 accp[4][2], accq[4][2], accv[4][2];
    #pragma unroll
    for (int i = 0; i < 4; i++)
        #pragma unroll
        for (int j = 0; j < 2; j++) {
            accp[i][j] = (f32x4){0,0,0,0};
            accq[i][j] = (f32x4){0,0,0,0};
            accv[i][j] = (f32x4){0,0,0,0};
        }

    for (int k0 = 0; k0 < EMB; k0 += 64) {
        #pragma unroll
        for (int ii = 0; ii < 4; ii++) {
            int slot = (ii * 4 + wave) * 64 + l;
            int r = slot >> 3, s = slot & 7;
            int g = s ^ (r & 7);
            async16(&As[slot * 8], xb + (m0 + r) * EMB + k0 + g * 8);
        }
        #pragma unroll
        for (int ii = 0; ii < 6; ii++) {
            int slot = (ii * 4 + wave) * 64 + l;
            int mat = slot >> 9, cc = slot & 511;
            int r = cc >> 3, s = cc & 7;
            int g = s ^ (r & 7);
            async16(&Bs[slot * 8],
                    wb + mat * (D1 * EMB) + (n0 + r) * EMB + k0 + g * 8);
        }
        __syncthreads();

        #pragma unroll
        for (int kk = 0; kk < 2; kk++) {
            bf16x8 af[4];
            #pragma unroll
            for (int mt = 0; mt < 4; mt++) {
                int row = wm * 64 + mt * 16 + col16;
                int sw = (q + 4 * kk) ^ (col16 & 7);
                af[mt] = *(const bf16x8*)&As[row * 64 + sw * 8];
            }
            bf16x8 bfr[3][2];
            #pragma unroll
            for (int mat = 0; mat < 3; mat++)
                #pragma unroll
                for (int nt = 0; nt < 2; nt++) {
                    int row = wn * 32 + nt * 16 + col16;
                    int sw = (q + 4 * kk) ^ (col16 & 7);
                    bfr[mat][nt] = *(const bf16x8*)&Bs[mat * 4096 + row * 64 + sw * 8];
                }
            #pragma unroll
            for (int mt = 0; mt < 4; mt++)
                #pragma unroll
                for (int nt = 0; nt < 2; nt++) {
                    accp[mt][nt] = __builtin_amdgcn_mfma_f32_16x16x32_bf16(
                        af[mt], bfr[0][nt], accp[mt][nt], 0, 0, 0);
                    accq[mt][nt] = __builtin_amdgcn_mfma_f32_16x16x32_bf16(
                        af[mt], bfr[1][nt], accq[mt][nt], 0, 0, 0);
                    accv[mt][nt] = __builtin_amdgcn_mfma_f32_16x16x32_bf16(
                        af[mt], bfr[2][nt], accv[mt][nt], 0, 0, 0);
                }
        }
        __syncthreads();
    }

    u16* scr = lds + wave * 2560;
    float pbv[2], qbv[2], vbv[2];
    #pragma unroll
    for (int nt = 0; nt < 2; nt++) {
        int n = n0 + wn * 32 + nt * 16 + col16;
        pbv[nt] = pb[n]; qbv[nt] = qb[n]; vbv[nt] = vb[n];
    }
    #pragma unroll
    for (int mt = 0; mt < 4; mt++)
        #pragma unroll
        for (int nt = 0; nt < 2; nt++)
            #pragma unroll
            for (int r = 0; r < 4; r++)
                scr[(mt * 16 + q * 4 + r) * 40 + nt * 16 + col16] =
                    f2bf(silu(accp[mt][nt][r] + pbv[nt]));
    #pragma unroll
    for (int k = 0; k < 4; k++) {
        int row = k * 16 + (l >> 2), cs = (l & 3) * 8;
        uint4 v = *(const uint4*)&scr[row * 40 + cs];
        *(uint4*)&P[(m0 + wm * 64 + row) * D1 + n0 + wn * 32 + cs] = v;
    }
    #pragma unroll
    for (int mt = 0; mt < 4; mt++)
        #pragma unroll
        for (int nt = 0; nt < 2; nt++)
            #pragma unroll
            for (int r = 0; r < 4; r++)
                scr[(mt * 16 + q * 4 + r) * 40 + nt * 16 + col16] =
                    f2bf(silu(accq[mt][nt][r] + qbv[nt]) *
                         silu(accv[mt][nt][r] + vbv[nt]));
    #pragma unroll
    for (int k = 0; k < 4; k++) {
        int row = k * 16 + (l >> 2), cs = (l & 3) * 8;
        uint4 v = *(const uint4*)&scr[row * 40 + cs];
        *(uint4*)&QV[(m0 + wm * 64 + row) * D1 + n0 + wn * 32 + cs] = v;
    }
}

// ---------------- tno kernels: d-tile 32, 8 i-groups x 8 rows --------------
// Thread (d = t&31, ig = t>>5), i0 = 8*ig (ig=7 computes discarded rows).
// Per jg: 1 q b128 + 3 aligned A b128, 32 FMAs. LDS strides 60 / 124
// (4*odd -> conflict-free b128, verified 0 conflicts in R4).
#define TNO_STAGE(QLOAD)                                                     \
    __shared__ float qs[32 * 60];                                            \
    __shared__ float asb[32 * 124];                                          \
    int t = threadIdx.x;                                                     \
    for (int idx = t; idx < 32 * 56; idx += 256) {                           \
        int d = idx & 31, j = idx >> 5;                                      \
        qs[d * 60 + j] = bf2f(QLOAD);                                        \
    }                                                                        \
    for (int idx = t; idx < 32 * 124; idx += 256) {                          \
        int d = idx & 31, p = idx >> 5;                                      \
        float v = 0.0f;                                                      \
        if (p <= 110) {                                                      \
            int lg = p - 55;                                                 \
            int rowi = lg + (lg < 0 ? 112 : 0);                              \
            v = Aco[rowi * D1 + d0 + d];                                     \
        }                                                                    \
        asb[d * 124 + p] = v;                                                \
    }                                                                        \
    __syncthreads();                                                         \
    int d = t & 31, ig = t >> 5;                                             \
    int i0 = ig * 8;                                                         \
    const float* aw = &asb[d * 124];                                         \
    const float* qw = &qs[d * 60];                                           \
    float acc[8] = {0,0,0,0,0,0,0,0};                                        \
    _Pragma("unroll")                                                        \
    for (int jg = 0; jg < 14; jg++) {                                        \
        f32x4 q4 = *(const f32x4*)&qw[jg * 4];                               \
        int base = i0 + 52 - 4 * jg;                                         \
        f32x4 a0 = *(const f32x4*)&aw[base];                                 \
        f32x4 a1 = *(const f32x4*)&aw[base + 4];                             \
        f32x4 a2 = *(const f32x4*)&aw[base + 8];                             \
        float aa[12] = { a0[0],a0[1],a0[2],a0[3],                            \
                         a1[0],a1[1],a1[2],a1[3],                            \
                         a2[0],a2[1],a2[2],a2[3] };                          \
        _Pragma("unroll")                                                    \
        for (int jj = 0; jj < 4; jj++) {                                     \
            float qv = q4[jj];                                               \
            _Pragma("unroll")                                                \
            for (int ii = 0; ii < 8; ii++)                                   \
                acc[ii] = fmaf(aa[ii + 3 - jj], qv, acc[ii]);                \
        }                                                                    \
    }

// ---------------- K3: Toeplitz along W -> O (bf16) ------------------------
__global__ __launch_bounds__(256) void tno_w_kernel(
    const u16* __restrict__ QV, const float* __restrict__ Aco,
    u16* __restrict__ O)
{
    int bh = blockIdx.x;            // b*56 + h
    int d0 = blockIdx.y * 32;
    TNO_STAGE(QV[(bh * 56 + j) * D1 + d0 + d])
    if (i0 < 56) {
        #pragma unroll
        for (int ii = 0; ii < 8; ii++)
            O[(bh * 56 + i0 + ii) * D1 + d0 + d] = f2bf(acc[ii]);
    }
}

// ---------------- K4: Toeplitz along H, fuse U = P .* (o1 + o2) -----------
__global__ __launch_bounds__(256) void tno_h_kernel(
    const u16* __restrict__ QV, const float* __restrict__ Aco,
    const u16* __restrict__ O, u16* __restrict__ PU)
{
    int bw = blockIdx.x;            // b*56 + w
    int b = bw / 56, wc = bw % 56;
    int d0 = blockIdx.y * 32;
    TNO_STAGE(QV[((b * 56 + j) * 56 + wc) * D1 + d0 + d])
    if (i0 < 56) {
        #pragma unroll
        for (int ii = 0; ii < 8; ii++) {
            int idx = ((b * 56 + i0 + ii) * 56 + wc) * D1 + d0 + d;
            float o = bf2f(O[idx]) + acc[ii];
            float p = bf2f(PU[idx]);
            PU[idx] = f2bf(p * o);
        }
    }
}

// ---------------- K5: MFMA outproj: out = U @ ow^T + ob -------------------
__global__ __launch_bounds__(256) void outproj_kernel(
    const u16* __restrict__ U, const u16* __restrict__ owb,
    const float* __restrict__ ob, float* __restrict__ out)
{
    __shared__ char ldsraw[36864];
    u16* As = (u16*)ldsraw;
    u16* Bs = (u16*)(ldsraw + 16384);
    int m0 = blockIdx.x * 128, n0 = blockIdx.y * 64;
    int t = threadIdx.x;
    int l = t & 63, wave = t >> 6;
    int wm = wave >> 1, wn = wave & 1;
    int col16 = l & 15, q = l >> 4;

    f32x4 acc[4][2];
    #pragma unroll
    for (int i = 0; i < 4; i++)
        #pragma unroll
        for (int j = 0; j < 2; j++) acc[i][j] = (f32x4){0,0,0,0};

    for (int k0 = 0; k0 < D1; k0 += 64) {
        #pragma unroll
        for (int ii = 0; ii < 4; ii++) {
            int slot = (ii * 4 + wave) * 64 + l;
            int r = slot >> 3, s = slot & 7;
            int g = s ^ (r & 7);
            async16(&As[slot * 8], U + (m0 + r) * D1 + k0 + g * 8);
        }
        #pragma unroll
        for (int ii = 0; ii < 2; ii++) {
            int slot = (ii * 4 + wave) * 64 + l;
            int r = slot >> 3, s = slot & 7;
            int g = s ^ (r & 7);
            async16(&Bs[slot * 8], owb + (n0 + r) * D1 + k0 + g * 8);
        }
        __syncthreads();

        #pragma unroll
        for (int kk = 0; kk < 2; kk++) {
            int sw = (q + 4 * kk) ^ (col16 & 7);
            bf16x8 af[4];
            #pragma unroll
            for (int mt = 0; mt < 4; mt++)
                af[mt] = *(const bf16x8*)&As[(wm * 64 + mt * 16 + col16) * 64 + sw * 8];
            bf16x8 bfr[2];
            #pragma unroll
            for (int nt = 0; nt < 2; nt++)
                bfr[nt] = *(const bf16x8*)&Bs[(wn * 32 + nt * 16 + col16) * 64 + sw * 8];
            #pragma unroll
            for (int mt = 0; mt < 4; mt++)
                #pragma unroll
                for (int nt = 0; nt < 2; nt++)
                    acc[mt][nt] = __builtin_amdgcn_mfma_f32_16x16x32_bf16(
                        af[mt], bfr[nt], acc[mt][nt], 0, 0, 0);
        }
        __syncthreads();
    }

    float* scr = (float*)ldsraw + wave * 2304;
    float obv[2];
    #pragma unroll
    for (int nt = 0; nt < 2; nt++)
        obv[nt] = ob[n0 + wn * 32 + nt * 16 + col16];
    #pragma unroll
    for (int mt = 0; mt < 4; mt++)
        #pragma unroll
        for (int nt = 0; nt < 2; nt++)
            #pragma unroll
            for (int r = 0; r < 4; r++)
                scr[(mt * 16 + q * 4 + r) * 36 + nt * 16 + col16] =
                    acc[mt][nt][r] + obv[nt];
    #pragma unroll
    for (int k = 0; k < 8; k++) {
        int row = k * 8 + (l >> 3), cs = (l & 7) * 4;
        f32x4 v = *(const f32x4*)&scr[row * 36 + cs];
        *(f32x4*)&out[(m0 + wm * 64 + row) * EMB + n0 + wn * 32 + cs] = v;
    }
}

extern "C" void kernel_launch(void* const* d_in, const int* in_sizes, int n_in,
                              void* d_out, int out_size, void* d_ws, size_t ws_size,
                              hipStream_t stream)
{
    (void)in_sizes; (void)n_in; (void)out_size; (void)ws_size;
    const float* x     = (const float*)d_in[0];
    const float* p_w   = (const float*)d_in[1];
    const float* p_b   = (const float*)d_in[2];
    const float* q_w   = (const float*)d_in[3];
    const float* q_b   = (const float*)d_in[4];
    const float* v_w   = (const float*)d_in[5];
    const float* v_b   = (const float*)d_in[6];
    const float* o_w   = (const float*)d_in[7];
    const float* o_b   = (const float*)d_in[8];
    const float* slope = (const float*)d_in[9];
    const float* t1_w0 = (const float*)d_in[10];
    const float* t1_b0 = (const float*)d_in[11];
    const float* t1_ws = (const float*)d_in[12];
    const float* t1_bs = (const float*)d_in[13];
    const float* t1_wo = (const float*)d_in[14];
    const float* t1_bo = (const float*)d_in[15];
    const float* t2_w0 = (const float*)d_in[16];
    const float* t2_b0 = (const float*)d_in[17];
    const float* t2_ws = (const float*)d_in[18];
    const float* t2_bs = (const float*)d_in[19];
    const float* t2_wo = (const float*)d_in[20];
    const float* t2_bo = (const float*)d_in[21];

    char* ws = (char*)d_ws;
    float* A1 = (float*)ws;                      // 258048 B
    float* A2 = (float*)(ws + 258048);           // 258048 B
    u16*   PU = (u16*)(ws + 516096);             // 28901376 B (P, later U)
    u16*   QV = (u16*)(ws + 29417472);           // 28901376 B
    u16*   O  = (u16*)(ws + 58318848);           // 28901376 B (bf16)
    u16*   xb = (u16*)(ws + 87220224);           // 9633792 B
    u16*   wb = (u16*)(ws + 96854016);           // 663552 B
    u16*   owb= (u16*)(ws + 97517568);           // 221184 B

    convert_kernel<<<(XCH + 4*WCH + 255) / 256, 256, 0, stream>>>(
        x, p_w, q_w, v_w, o_w, xb, wb, owb);
    rpe_kernel<<<224, 576, 0, stream>>>(slope,
        t1_w0, t1_b0, t1_ws, t1_bs, t1_wo, t1_bo,
        t2_w0, t2_b0, t2_ws, t2_bs, t2_wo, t2_bo, A1, A2);
    proj_kernel<<<dim3(TOK / 128, D1 / 64), 256, 0, stream>>>(
        xb, wb, p_b, q_b, v_b, PU, QV);
    tno_w_kernel<<<dim3(NB * NN, D1 / 32), 256, 0, stream>>>(QV, A1, O);
    tno_h_kernel<<<dim3(NB * NN, D1 / 32), 256, 0, stream>>>(QV, A2, O, PU);
    outproj_kernel<<<dim3(TOK / 128, EMB / 64), 256, 0, stream>>>(
        PU, owb, o_b, (float*)d_out);
}

// Round 6
// 249.759 us; speedup vs baseline: 1.1721x; 1.1721x over previous
//
#include <hip/hip_runtime.h>
#include <hip/hip_bf16.h>
#include <math.h>

typedef unsigned short u16;
typedef short bf16x8 __attribute__((ext_vector_type(8)));
typedef float f32x4 __attribute__((ext_vector_type(4)));

#define NB 8
#define NN 56          // h == w
#define M2 112         // 2n
#define EMB 192
#define D1 576
#define TOK (NB*NN*NN) // 25088

__device__ __forceinline__ float bf2f(unsigned int u) {
    union { unsigned int i; float f; } v; v.i = u << 16; return v.f;
}
__device__ __forceinline__ u16 f2bf(float f) {
    union { float f; unsigned int i; } v; v.f = f;
    unsigned int x = v.i;
    return (u16)((x + 0x7fffu + ((x >> 16) & 1u)) >> 16);
}
__device__ __forceinline__ float silu(float x) {
    return x / (1.0f + __expf(-x));
}
__device__ __forceinline__ void async16(void* lds, const void* g) {
    __builtin_amdgcn_global_load_lds(
        (const __attribute__((address_space(1))) void*)g,
        (__attribute__((address_space(3))) void*)lds, 16, 0, 0);
}

// ---------------- K0: fp32 -> bf16 convert (x, pw, qw, vw, ow) ------------
#define XCH (TOK*EMB/4)
#define WCH (D1*EMB/4)
__global__ __launch_bounds__(256) void convert_kernel(
    const float* __restrict__ x,
    const float* __restrict__ pw, const float* __restrict__ qw,
    const float* __restrict__ vw, const float* __restrict__ ow,
    u16* __restrict__ xb, u16* __restrict__ wb, u16* __restrict__ owb)
{
    int tid = blockIdx.x * 256 + threadIdx.x;
    const float* src; u16* dst; int off;
    if (tid < XCH) { src = x; dst = xb; off = tid; }
    else {
        int r = tid - XCH;
        int seg = r / WCH; off = r % WCH;
        if (seg == 0)      { src = pw; dst = wb; }
        else if (seg == 1) { src = qw; dst = wb + D1*EMB; }
        else if (seg == 2) { src = vw; dst = wb + 2*D1*EMB; }
        else if (seg == 3) { src = ow; dst = owb; }
        else return;
    }
    float4 f = *(const float4*)(src + off * 4);
    ushort4 o;
    o.x = f2bf(f.x); o.y = f2bf(f.y); o.z = f2bf(f.z); o.w = f2bf(f.w);
    *(ushort4*)(dst + off * 4) = o;
}

// ---------------- K1: RPE MLP + decay -> A1, A2 (fp32, 112 x 576 each) ----
__global__ __launch_bounds__(576) void rpe_kernel(
    const float* __restrict__ slope,
    const float* w0a, const float* b0a, const float* wsa, const float* bsa,
    const float* woa, const float* boa,
    const float* w0b, const float* b0b, const float* wsb, const float* bsb,
    const float* wob, const float* bob,
    float* __restrict__ A1, float* __restrict__ A2)
{
    int wq  = blockIdx.x / M2;
    int row = blockIdx.x % M2;
    const float* w0 = wq ? w0b : w0a;  const float* b0 = wq ? b0b : b0a;
    const float* ws = wq ? wsb : wsa;  const float* bs = wq ? bsb : bsa;
    const float* wo = wq ? wob : woa;  const float* bo = wq ? bob : boa;
    float* A = wq ? A2 : A1;

    float tval = (row == 0 || row == 56) ? 0.0f
               : (row < 56 ? (float)row : -(float)(row - 56));
    int kexp = (row == 0 || row == 56) ? 0 : (row < 56 ? row : 112 - row);

    __shared__ float h[32], g[32];
    int t = threadIdx.x;
    if (t < 32) h[t] = tval * w0[t] + b0[t];
    __syncthreads();
    for (int L = 0; L < 3; L++) {
        if (t < 32) g[t] = fmaxf(h[t], 0.0f);
        __syncthreads();
        float hn = 0.0f;
        if (t < 32) {
            hn = bs[L * 32 + t];
            for (int k = 0; k < 32; k++)
                hn = fmaf(g[k], ws[(L * 32 + t) * 32 + k], hn);
        }
        __syncthreads();
        if (t < 32) h[t] = hn;
        __syncthreads();
    }
    if (t < 32) g[t] = fmaxf(h[t], 0.0f);
    __syncthreads();

    float o = bo[t];
    for (int k = 0; k < 32; k++)
        o = fmaf(g[k], wo[t * 32 + k], o);

    float sl = slope[t];
    sl = 0.95f + 0.05f * fminf(fmaxf(sl, 0.0f), 1.0f);
    float dec = powf(sl, (float)kexp);
    A[row * D1 + t] = o * dec;
}

// ---------------- K2: MFMA proj --------------------------------------------
__global__ __launch_bounds__(256) void proj_kernel(
    const u16* __restrict__ xb, const u16* __restrict__ wb,
    const float* __restrict__ pb, const float* __restrict__ qb,
    const float* __restrict__ vb,
    u16* __restrict__ P, u16* __restrict__ QV)
{
    __shared__ u16 lds[20480];          // 40 KB: As 8192 u16, Bs 12288 u16
    u16* As = lds;
    u16* Bs = lds + 8192;
    int m0 = blockIdx.x * 128, n0 = blockIdx.y * 64;
    int t = threadIdx.x;
    int l = t & 63, wave = t >> 6;
    int wm = wave >> 1, wn = wave & 1;
    int col16 = l & 15, q = l >> 4;

    f32x4 accp[4][2], accq[4][2], accv[4][2];
    #pragma unroll
    for (int i = 0; i < 4; i++)
        #pragma unroll
        for (int j = 0; j < 2; j++) {
            accp[i][j] = (f32x4){0,0,0,0};
            accq[i][j] = (f32x4){0,0,0,0};
            accv[i][j] = (f32x4){0,0,0,0};
        }

    for (int k0 = 0; k0 < EMB; k0 += 64) {
        #pragma unroll
        for (int ii = 0; ii < 4; ii++) {
            int slot = (ii * 4 + wave) * 64 + l;
            int r = slot >> 3, s = slot & 7;
            int g = s ^ (r & 7);
            async16(&As[slot * 8], xb + (m0 + r) * EMB + k0 + g * 8);
        }
        #pragma unroll
        for (int ii = 0; ii < 6; ii++) {
            int slot = (ii * 4 + wave) * 64 + l;
            int mat = slot >> 9, cc = slot & 511;
            int r = cc >> 3, s = cc & 7;
            int g = s ^ (r & 7);
            async16(&Bs[slot * 8],
                    wb + mat * (D1 * EMB) + (n0 + r) * EMB + k0 + g * 8);
        }
        __syncthreads();

        #pragma unroll
        for (int kk = 0; kk < 2; kk++) {
            bf16x8 af[4];
            #pragma unroll
            for (int mt = 0; mt < 4; mt++) {
                int row = wm * 64 + mt * 16 + col16;
                int sw = (q + 4 * kk) ^ (col16 & 7);
                af[mt] = *(const bf16x8*)&As[row * 64 + sw * 8];
            }
            bf16x8 bfr[3][2];
            #pragma unroll
            for (int mat = 0; mat < 3; mat++)
                #pragma unroll
                for (int nt = 0; nt < 2; nt++) {
                    int row = wn * 32 + nt * 16 + col16;
                    int sw = (q + 4 * kk) ^ (col16 & 7);
                    bfr[mat][nt] = *(const bf16x8*)&Bs[mat * 4096 + row * 64 + sw * 8];
                }
            #pragma unroll
            for (int mt = 0; mt < 4; mt++)
                #pragma unroll
                for (int nt = 0; nt < 2; nt++) {
                    accp[mt][nt] = __builtin_amdgcn_mfma_f32_16x16x32_bf16(
                        af[mt], bfr[0][nt], accp[mt][nt], 0, 0, 0);
                    accq[mt][nt] = __builtin_amdgcn_mfma_f32_16x16x32_bf16(
                        af[mt], bfr[1][nt], accq[mt][nt], 0, 0, 0);
                    accv[mt][nt] = __builtin_amdgcn_mfma_f32_16x16x32_bf16(
                        af[mt], bfr[2][nt], accv[mt][nt], 0, 0, 0);
                }
        }
        __syncthreads();
    }

    u16* scr = lds + wave * 2560;
    float pbv[2], qbv[2], vbv[2];
    #pragma unroll
    for (int nt = 0; nt < 2; nt++) {
        int n = n0 + wn * 32 + nt * 16 + col16;
        pbv[nt] = pb[n]; qbv[nt] = qb[n]; vbv[nt] = vb[n];
    }
    #pragma unroll
    for (int mt = 0; mt < 4; mt++)
        #pragma unroll
        for (int nt = 0; nt < 2; nt++)
            #pragma unroll
            for (int r = 0; r < 4; r++)
                scr[(mt * 16 + q * 4 + r) * 40 + nt * 16 + col16] =
                    f2bf(silu(accp[mt][nt][r] + pbv[nt]));
    #pragma unroll
    for (int k = 0; k < 4; k++) {
        int row = k * 16 + (l >> 2), cs = (l & 3) * 8;
        uint4 v = *(const uint4*)&scr[row * 40 + cs];
        *(uint4*)&P[(m0 + wm * 64 + row) * D1 + n0 + wn * 32 + cs] = v;
    }
    #pragma unroll
    for (int mt = 0; mt < 4; mt++)
        #pragma unroll
        for (int nt = 0; nt < 2; nt++)
            #pragma unroll
            for (int r = 0; r < 4; r++)
                scr[(mt * 16 + q * 4 + r) * 40 + nt * 16 + col16] =
                    f2bf(silu(accq[mt][nt][r] + qbv[nt]) *
                         silu(accv[mt][nt][r] + vbv[nt]));
    #pragma unroll
    for (int k = 0; k < 4; k++) {
        int row = k * 16 + (l >> 2), cs = (l & 3) * 8;
        uint4 v = *(const uint4*)&scr[row * 40 + cs];
        *(uint4*)&QV[(m0 + wm * 64 + row) * D1 + n0 + wn * 32 + cs] = v;
    }
}

// ---------------- tno kernels: 2 rows/block, d-tile 32, 8 ig x 8 i ---------
// Thread (d = t&31, ig = t>>5), i0 = 8*ig (ig=7 discarded).
// asb[d][p] stride 124 (4*31): b128 quad = (31d+pg) mod 8 -> conflict-free.
// Staged with per-thread b128 writes (4 consecutive p) - conflict-free.
// qs[r][d][j] stride 60: b64 pair-writes (2-way = free), b128 reads ok.
#define TNO_STAGE2(QLOAD)                                                    \
    __shared__ float qs[2 * 32 * 60];                                        \
    __shared__ float asb[32 * 124];                                          \
    int t = threadIdx.x;                                                     \
    {                                                                        \
        int d = t & 31, sub = t >> 5;                                        \
        _Pragma("unroll")                                                    \
        for (int s = 0; s < 7; s++) {                                        \
            int pairidx = sub * 7 + s;       /* 0..55 */                     \
            int r = pairidx / 28;                                            \
            int j2 = pairidx % 28;                                           \
            int j = j2 * 2;                                                  \
            float q0, q1;                                                    \
            { int jj = j;     q0 = bf2f(QLOAD); }                            \
            { int jj = j + 1; q1 = bf2f(QLOAD); }                            \
            *(float2*)&qs[r * 1920 + d * 60 + j] = make_float2(q0, q1);      \
        }                                                                    \
        _Pragma("unroll")                                                    \
        for (int it = 0; it < 4; it++) {                                     \
            int pg = sub + 8 * it;           /* 0..31 */                     \
            if (pg < 31) {                                                   \
                f32x4 v;                                                     \
                _Pragma("unroll")                                            \
                for (int k = 0; k < 4; k++) {                                \
                    int p = pg * 4 + k;                                      \
                    float a = 0.0f;                                          \
                    if (p <= 110) {                                          \
                        int lg = p - 55;                                     \
                        int rowi = lg + (lg < 0 ? 112 : 0);                  \
                        a = Aco[rowi * D1 + d0 + d];                         \
                    }                                                        \
                    v[k] = a;                                                \
                }                                                            \
                *(f32x4*)&asb[d * 124 + pg * 4] = v;                         \
            }                                                                \
        }                                                                    \
    }                                                                        \
    __syncthreads();                                                         \
    int d = t & 31, ig = t >> 5;                                             \
    int i0 = ig * 8;                                                         \
    const float* aw = &asb[d * 124];                                         \
    const float* qw0 = &qs[d * 60];                                          \
    const float* qw1 = &qs[1920 + d * 60];                                   \
    float acc0[8] = {0,0,0,0,0,0,0,0};                                       \
    float acc1[8] = {0,0,0,0,0,0,0,0};                                       \
    _Pragma("unroll")                                                        \
    for (int jg = 0; jg < 14; jg++) {                                        \
        f32x4 qa = *(const f32x4*)&qw0[jg * 4];                              \
        f32x4 qb_ = *(const f32x4*)&qw1[jg * 4];                             \
        int base = i0 + 52 - 4 * jg;                                         \
        f32x4 a0 = *(const f32x4*)&aw[base];                                 \
        f32x4 a1 = *(const f32x4*)&aw[base + 4];                             \
        f32x4 a2 = *(const f32x4*)&aw[base + 8];                             \
        float aa[12] = { a0[0],a0[1],a0[2],a0[3],                            \
                         a1[0],a1[1],a1[2],a1[3],                            \
                         a2[0],a2[1],a2[2],a2[3] };                          \
        _Pragma("unroll")                                                    \
        for (int jj = 0; jj < 4; jj++) {                                     \
            float qv0 = qa[jj], qv1 = qb_[jj];                               \
            _Pragma("unroll")                                                \
            for (int ii = 0; ii < 8; ii++) {                                 \
                acc0[ii] = fmaf(aa[ii + 3 - jj], qv0, acc0[ii]);             \
                acc1[ii] = fmaf(aa[ii + 3 - jj], qv1, acc1[ii]);             \
            }                                                                \
        }                                                                    \
    }

// ---------------- K3: Toeplitz along W -> O (bf16) ------------------------
__global__ __launch_bounds__(256) void tno_w_kernel(
    const u16* __restrict__ QV, const float* __restrict__ Aco,
    u16* __restrict__ O)
{
    int bh0 = blockIdx.x * 2;       // two consecutive b*56+h rows
    int d0 = blockIdx.y * 32;
    TNO_STAGE2(QV[((bh0 + r) * 56 + jj) * D1 + d0 + d])
    if (i0 < 56) {
        #pragma unroll
        for (int ii = 0; ii < 8; ii++) {
            O[(bh0 * 56 + (i0 + ii)) * D1 + d0 + d]       = f2bf(acc0[ii]);
            O[((bh0 + 1) * 56 + (i0 + ii)) * D1 + d0 + d] = f2bf(acc1[ii]);
        }
    }
}

// ---------------- K4: Toeplitz along H, fuse U = P .* (o1 + o2) -----------
__global__ __launch_bounds__(256) void tno_h_kernel(
    const u16* __restrict__ QV, const float* __restrict__ Aco,
    const u16* __restrict__ O, u16* __restrict__ PU)
{
    int bw0 = blockIdx.x * 2;       // two consecutive b*56+w columns
    int d0 = blockIdx.y * 32;
    TNO_STAGE2(QV[(((bw0 + r) / 56 * 56 + jj) * 56 + ((bw0 + r) % 56)) * D1 + d0 + d])
    int b0c = bw0 / 56, w0c = bw0 % 56;
    int b1c = (bw0 + 1) / 56, w1c = (bw0 + 1) % 56;
    if (i0 < 56) {
        #pragma unroll
        for (int ii = 0; ii < 8; ii++) {
            int i = i0 + ii;
            int idx0 = ((b0c * 56 + i) * 56 + w0c) * D1 + d0 + d;
            float o0 = bf2f(O[idx0]) + acc0[ii];
            float p0 = bf2f(PU[idx0]);
            PU[idx0] = f2bf(p0 * o0);
            int idx1 = ((b1c * 56 + i) * 56 + w1c) * D1 + d0 + d;
            float o1v = bf2f(O[idx1]) + acc1[ii];
            float p1 = bf2f(PU[idx1]);
            PU[idx1] = f2bf(p1 * o1v);
        }
    }
}

// ---------------- K5: MFMA outproj: out = U @ ow^T + ob -------------------
__global__ __launch_bounds__(256) void outproj_kernel(
    const u16* __restrict__ U, const u16* __restrict__ owb,
    const float* __restrict__ ob, float* __restrict__ out)
{
    __shared__ char ldsraw[36864];
    u16* As = (u16*)ldsraw;
    u16* Bs = (u16*)(ldsraw + 16384);
    int m0 = blockIdx.x * 128, n0 = blockIdx.y * 64;
    int t = threadIdx.x;
    int l = t & 63, wave = t >> 6;
    int wm = wave >> 1, wn = wave & 1;
    int col16 = l & 15, q = l >> 4;

    f32x4 acc[4][2];
    #pragma unroll
    for (int i = 0; i < 4; i++)
        #pragma unroll
        for (int j = 0; j < 2; j++) acc[i][j] = (f32x4){0,0,0,0};

    for (int k0 = 0; k0 < D1; k0 += 64) {
        #pragma unroll
        for (int ii = 0; ii < 4; ii++) {
            int slot = (ii * 4 + wave) * 64 + l;
            int r = slot >> 3, s = slot & 7;
            int g = s ^ (r & 7);
            async16(&As[slot * 8], U + (m0 + r) * D1 + k0 + g * 8);
        }
        #pragma unroll
        for (int ii = 0; ii < 2; ii++) {
            int slot = (ii * 4 + wave) * 64 + l;
            int r = slot >> 3, s = slot & 7;
            int g = s ^ (r & 7);
            async16(&Bs[slot * 8], owb + (n0 + r) * D1 + k0 + g * 8);
        }
        __syncthreads();

        #pragma unroll
        for (int kk = 0; kk < 2; kk++) {
            int sw = (q + 4 * kk) ^ (col16 & 7);
            bf16x8 af[4];
            #pragma unroll
            for (int mt = 0; mt < 4; mt++)
                af[mt] = *(const bf16x8*)&As[(wm * 64 + mt * 16 + col16) * 64 + sw * 8];
            bf16x8 bfr[2];
            #pragma unroll
            for (int nt = 0; nt < 2; nt++)
                bfr[nt] = *(const bf16x8*)&Bs[(wn * 32 + nt * 16 + col16) * 64 + sw * 8];
            #pragma unroll
            for (int mt = 0; mt < 4; mt++)
                #pragma unroll
                for (int nt = 0; nt < 2; nt++)
                    acc[mt][nt] = __builtin_amdgcn_mfma_f32_16x16x32_bf16(
                        af[mt], bfr[nt], acc[mt][nt], 0, 0, 0);
        }
        __syncthreads();
    }

    float* scr = (float*)ldsraw + wave * 2304;
    float obv[2];
    #pragma unroll
    for (int nt = 0; nt < 2; nt++)
        obv[nt] = ob[n0 + wn * 32 + nt * 16 + col16];
    #pragma unroll
    for (int mt = 0; mt < 4; mt++)
        #pragma unroll
        for (int nt = 0; nt < 2; nt++)
            #pragma unroll
            for (int r = 0; r < 4; r++)
                scr[(mt * 16 + q * 4 + r) * 36 + nt * 16 + col16] =
                    acc[mt][nt][r] + obv[nt];
    #pragma unroll
    for (int k = 0; k < 8; k++) {
        int row = k * 8 + (l >> 3), cs = (l & 7) * 4;
        f32x4 v = *(const f32x4*)&scr[row * 36 + cs];
        *(f32x4*)&out[(m0 + wm * 64 + row) * EMB + n0 + wn * 32 + cs] = v;
    }
}

extern "C" void kernel_launch(void* const* d_in, const int* in_sizes, int n_in,
                              void* d_out, int out_size, void* d_ws, size_t ws_size,
                              hipStream_t stream)
{
    (void)in_sizes; (void)n_in; (void)out_size; (void)ws_size;
    const float* x     = (const float*)d_in[0];
    const float* p_w   = (const float*)d_in[1];
    const float* p_b   = (const float*)d_in[2];
    const float* q_w   = (const float*)d_in[3];
    const float* q_b   = (const float*)d_in[4];
    const float* v_w   = (const float*)d_in[5];
    const float* v_b   = (const float*)d_in[6];
    const float* o_w   = (const float*)d_in[7];
    const float* o_b   = (const float*)d_in[8];
    const float* slope = (const float*)d_in[9];
    const float* t1_w0 = (const float*)d_in[10];
    const float* t1_b0 = (const float*)d_in[11];
    const float* t1_ws = (const float*)d_in[12];
    const float* t1_bs = (const float*)d_in[13];
    const float* t1_wo = (const float*)d_in[14];
    const float* t1_bo = (const float*)d_in[15];
    const float* t2_w0 = (const float*)d_in[16];
    const float* t2_b0 = (const float*)d_in[17];
    const float* t2_ws = (const float*)d_in[18];
    const float* t2_bs = (const float*)d_in[19];
    const float* t2_wo = (const float*)d_in[20];
    const float* t2_bo = (const float*)d_in[21];

    char* ws = (char*)d_ws;
    float* A1 = (float*)ws;                      // 258048 B
    float* A2 = (float*)(ws + 258048);           // 258048 B
    u16*   PU = (u16*)(ws + 516096);             // 28901376 B (P, later U)
    u16*   QV = (u16*)(ws + 29417472);           // 28901376 B
    u16*   O  = (u16*)(ws + 58318848);           // 28901376 B (bf16)
    u16*   xb = (u16*)(ws + 87220224);           // 9633792 B
    u16*   wb = (u16*)(ws + 96854016);           // 663552 B
    u16*   owb= (u16*)(ws + 97517568);           // 221184 B

    convert_kernel<<<(XCH + 4*WCH + 255) / 256, 256, 0, stream>>>(
        x, p_w, q_w, v_w, o_w, xb, wb, owb);
    rpe_kernel<<<224, 576, 0, stream>>>(slope,
        t1_w0, t1_b0, t1_ws, t1_bs, t1_wo, t1_bo,
        t2_w0, t2_b0, t2_ws, t2_bs, t2_wo, t2_bo, A1, A2);
    proj_kernel<<<dim3(TOK / 128, D1 / 64), 256, 0, stream>>>(
        xb, wb, p_b, q_b, v_b, PU, QV);
    tno_w_kernel<<<dim3(NB * NN / 2, D1 / 32), 256, 0, stream>>>(QV, A1, O);
    tno_h_kernel<<<dim3(NB * NN / 2, D1 / 32), 256, 0, stream>>>(QV, A2, O, PU);
    outproj_kernel<<<dim3(TOK / 128, EMB / 64), 256, 0, stream>>>(
        PU, owb, o_b, (float*)d_out);
}